// Round 13
// baseline (1627.541 us; speedup 1.0000x reference)
//
#include <hip/hip_runtime.h>
#include <math.h>

#define WIN 11
#define PAD 5

typedef float v2f __attribute__((ext_vector_type(2)));

struct GW { float g[WIN]; };

// ---------------------------------------------------------------------------
// SINGLE-DISPATCH MS-SSIM. R0-R12 model: aggregate per-SIMD row throughput
// saturates at ~1100 cyc/row independent of wave count (R0 vs R2), so total
// time ~= total wave-rows / 1024 SIMDs x 1100cyc -- IF every phase runs at
// saturation. R5/R12's separate rest dispatch ran at 2 waves/SIMD (below
// saturation) + dispatch gaps = ~120us for ~35us of work. Fix: avg_pool2^l
// is a mean over a 2^l x 2^l original block (pooling is linear), so rest
// tiles pool DIRECTLY from the original images on the fly -> no pyramid
// buffers, no pool dispatch, no inter-dispatch dependency. ONE kernel:
//   blocks <1536 : L0 tiles (R5 ring tile, EMIT path deleted entirely)
//   blocks >=1536: L1..L4 tiles (R2-proven shift-register tile + pooled
//                  branchless LOAD; S = 2,4,8,16 consecutive floats =
//                  float2/float4 vector loads, sums scaled by 1/S^2)
//   final loss   : last-block-done counter (R12-verified pattern)
// Compiler facts preserved: scalar float[11] accumulators inline (the
// double-row/packed family spills under every delivery mechanism, R1/R7-R10);
// tile bodies are __forceinline__ functions taking NO array params.
// Tripwire: WRITE_SIZE must be <1MB now (no pyramid); growth = scratch.
// ---------------------------------------------------------------------------

template<int S>
__device__ __forceinline__ float sumS(const float* __restrict__ p)
{
    if constexpr (S == 2) {
        float2 v = *(const float2*)p; return v.x + v.y;
    } else if constexpr (S == 4) {
        float4 v = *(const float4*)p; return (v.x + v.y) + (v.z + v.w);
    } else {
        float s = 0.f;
#pragma unroll
        for (int j = 0; j < S; j += 4) {
            float4 v = *(const float4*)(p + j);
            s += (v.x + v.y) + (v.z + v.w);
        }
        return s;
    }
}

// ---- L0 tile: R5 ring tile verbatim, EMIT path removed (VGPR 56 proven) ----
__device__ __forceinline__ float ssim_tile_l0(
    const float* __restrict__ p1, const float* __restrict__ p2,
    int X0, int Y0, const GW& gw, float2* __restrict__ rb)
{
    constexpr int W = 512;
    const int TH = 32;
    const int lane = threadIdx.x & 63;
    const int gx = X0 + lane;
    const bool cval = gx < W;
    const int hx   = (lane < 5) ? (X0 - 5 + lane) : (X0 + 59 + lane);
    const bool hval = (lane < 10) && ((unsigned)hx < (unsigned)W);
    const int hpos = (lane < 5) ? lane : (64 + lane);      // 0..4 | 69..73
    const int cpos = 5 + lane;
    const int gxc = cval ? gx : 0;
    const int hxc = hval ? hx : gxc;
    const int wpos = (lane < 10) ? hpos : cpos;

    float vMp[11], vSp[11], vMq[11], vSq[11];
#pragma unroll
    for (int k = 0; k < 11; ++k) { vMp[k] = 0.f; vSp[k] = 0.f; vMq[k] = 0.f; vSq[k] = 0.f; }

    float part = 0.f;

    auto LOAD = [&](int t, float& oa, float& ob, float& oah, float& obh) {
        int y = Y0 - PAD + t;
        bool yin = (unsigned)y < (unsigned)W;
        const float* r1 = p1 + (size_t)(yin ? y : 0) * W;
        const float* r2 = p2 + (size_t)(yin ? y : 0) * W;
        float va = r1[gxc], vb = r2[gxc];
        float wa = r1[hxc], wb = r2[hxc];
        bool cv = yin && cval;
        bool hv = yin && hval;
        oa  = cv ? va : 0.f;
        ob  = cv ? vb : 0.f;
        oah = hv ? wa : 0.f;
        obh = hv ? wb : 0.f;
    };

    float a0, b0, ah0, bh0;
    float a1, b1, ah1, bh1;
    LOAD(0, a0, b0, ah0, bh0);
    LOAD(1, a1, b1, ah1, bh1);

#pragma unroll 1
    for (int blk = 0; blk < 4; ++blk) {
#pragma unroll
        for (int u = 0; u < 11; ++u) {
            const int t = blk * 11 + u;        // u compile-time, blk runtime

            float a2, b2, ah2, bh2;
            LOAD(t + 2, a2, b2, ah2, bh2);

            float p = a0 + b0, q = a0 - b0;
            float ph = ah0 + bh0, qh = ah0 - bh0;
            rb[cpos] = make_float2(p, q);
            rb[wpos] = (lane < 10) ? make_float2(ph, qh) : make_float2(p, q);
            __builtin_amdgcn_wave_barrier();   // writes -> reads

            v2f hM = {0.f, 0.f}, hS = {0.f, 0.f};
#pragma unroll
            for (int j = 0; j < WIN; ++j) {
                float2 v = rb[lane + j];
                v2f vm = { v.x, v.y };
                v2f g2 = { gw.g[j], gw.g[j] };
                hM = __builtin_elementwise_fma(g2, vm, hM);
                hS = __builtin_elementwise_fma(g2, vm * vm, hS);
            }
            __builtin_amdgcn_wave_barrier();   // reads -> next writes
            float hp = hM.x, hq = hM.y, hpp = hS.x, hqq = hS.y;

#pragma unroll
            for (int s = 0; s < 11; ++s) {
                const int widx = 10 - ((s - u + 11) % 11);
                float g = gw.g[widx];
                vMp[s] = fmaf(g, hp,  vMp[s]);
                vSp[s] = fmaf(g, hpp, vSp[s]);
                vMq[s] = fmaf(g, hq,  vMq[s]);
                vSq[s] = fmaf(g, hqq, vSq[s]);
            }

            {
                int o = t - 10;
                if ((unsigned)o < (unsigned)TH) {
                    float Mp = vMp[u], Sp_ = vSp[u], Mq = vMq[u], Sq_ = vSq[u];
                    const float C1v = 1e-4f, C2v = 9e-4f;
                    float A = Mp * Mp, B = Mq * Mq;
                    float ABp = A + B, ABm = A - B;
                    float SSp = Sp_ + Sq_, SSm = Sp_ - Sq_;
                    float n1 = fmaf(0.5f, ABm, C1v);
                    float n2 = fmaf(0.5f, SSm - ABm, C2v);
                    float e1 = fmaf(0.5f, ABp, C1v);
                    float e2 = fmaf(0.5f, SSp - ABp, C2v);
                    float v = (n1 * n2) * __builtin_amdgcn_rcpf(e1 * e2);
                    part += cval ? v : 0.f;
                }
                vMp[u] = 0.f; vSp[u] = 0.f; vMq[u] = 0.f; vSq[u] = 0.f;
            }

            a0 = a1; b0 = b1; ah0 = ah1; bh0 = bh1;
            a1 = a2; b1 = b2; ah1 = ah2; bh1 = bh2;

            __builtin_amdgcn_sched_barrier(0);
        }
    }

    return part;
}

// ---- L1..L4 tile: R2-proven shift-register shape + pool-on-the-fly LOAD ----
// Level width W = 512/S is compile-time. For S>=8 the halo is provably out
// of range at every valid tile origin -> skipped at compile time.
template<int S>
__device__ __forceinline__ float ssim_tile_pool(
    const float* __restrict__ p1, const float* __restrict__ p2,
    int X0, int Y0, const GW& gw, float2* __restrict__ rb)
{
    constexpr int W = 512 / S;
    const int lane = threadIdx.x & 63;
    const int gx = X0 + lane;
    const bool cval = gx < W;
    const int hx   = (lane < 5) ? (X0 - 5 + lane) : (X0 + 59 + lane);
    const bool hval = (lane < 10) && ((unsigned)hx < (unsigned)W);
    const int hpos = (lane < 5) ? lane : (64 + lane);
    const int cpos = 5 + lane;
    const int gxc = cval ? gx : 0;
    const int hxc = hval ? hx : gxc;
    const int wpos = (lane < 10) ? hpos : cpos;

    float vMp[11], vSp[11], vMq[11], vSq[11];
#pragma unroll
    for (int k = 0; k < 11; ++k) { vMp[k] = 0.f; vSp[k] = 0.f; vMq[k] = 0.f; vSq[k] = 0.f; }

    float part = 0.f;

    auto LOAD = [&](int t, float& oa, float& ob, float& oah, float& obh) {
        int y = Y0 - PAD + t;                          // level-l row
        bool yin = (unsigned)y < (unsigned)W;
        const float* r1 = p1 + (size_t)(yin ? y : 0) * (512 * S);
        const float* r2 = p2 + (size_t)(yin ? y : 0) * (512 * S);
        constexpr float inv = 1.f / (float)(S * S);
        float sa = 0.f, sb = 0.f;
#pragma unroll
        for (int i = 0; i < S; ++i) {
            sa += sumS<S>(r1 + i * 512 + gxc * S);
            sb += sumS<S>(r2 + i * 512 + gxc * S);
        }
        bool cv = yin && cval;
        oa = cv ? sa * inv : 0.f;
        ob = cv ? sb * inv : 0.f;
        if constexpr (S >= 8) {
            // W<=64: halo cols are out of range at every tile origin
            oah = 0.f; obh = 0.f;
        } else {
            float sha = 0.f, shb = 0.f;
#pragma unroll
            for (int i = 0; i < S; ++i) {
                sha += sumS<S>(r1 + i * 512 + hxc * S);
                shb += sumS<S>(r2 + i * 512 + hxc * S);
            }
            bool hv = yin && hval;
            oah = hv ? sha * inv : 0.f;
            obh = hv ? shb * inv : 0.f;
        }
    };

    float a, b, ah, bh;
    LOAD(0, a, b, ah, bh);

#pragma unroll 2
    for (int t = 0; t < 42; ++t) {
        float na, nb, nah, nbh;
        LOAD(t + 1, na, nb, nah, nbh);

        float p = a + b, q = a - b;
        float ph = ah + bh, qh = ah - bh;
        rb[cpos] = make_float2(p, q);
        rb[wpos] = (lane < 10) ? make_float2(ph, qh) : make_float2(p, q);
        __builtin_amdgcn_wave_barrier();

        v2f hM = {0.f, 0.f}, hS = {0.f, 0.f};
#pragma unroll
        for (int j = 0; j < WIN; ++j) {
            float2 v = rb[lane + j];
            v2f vm = { v.x, v.y };
            v2f g2 = { gw.g[j], gw.g[j] };
            hM = __builtin_elementwise_fma(g2, vm, hM);
            hS = __builtin_elementwise_fma(g2, vm * vm, hS);
        }
        __builtin_amdgcn_wave_barrier();
        float hp = hM.x, hq = hM.y, hpp = hS.x, hqq = hS.y;

#pragma unroll
        for (int k = 0; k < 11; ++k) {
            float g = gw.g[10 - k];
            vMp[k] = fmaf(g, hp,  vMp[k]);
            vSp[k] = fmaf(g, hpp, vSp[k]);
            vMq[k] = fmaf(g, hq,  vMq[k]);
            vSq[k] = fmaf(g, hqq, vSq[k]);
        }

        if (t >= 10) {
            int o = t - 10;
            bool yok = (unsigned)(Y0 + o) < (unsigned)W;
            float Mp = vMp[0], Sp_ = vSp[0], Mq = vMq[0], Sq_ = vSq[0];
            const float C1v = 1e-4f, C2v = 9e-4f;
            float A = Mp * Mp, B = Mq * Mq;
            float ABp = A + B, ABm = A - B;
            float SSp = Sp_ + Sq_, SSm = Sp_ - Sq_;
            float n1 = fmaf(0.5f, ABm, C1v);
            float n2 = fmaf(0.5f, SSm - ABm, C2v);
            float e1 = fmaf(0.5f, ABp, C1v);
            float e2 = fmaf(0.5f, SSp - ABp, C2v);
            float v = (n1 * n2) * __builtin_amdgcn_rcpf(e1 * e2);
            part += (cval && yok) ? v : 0.f;
        }

#pragma unroll
        for (int k = 0; k < 10; ++k) {
            vMp[k] = vMp[k + 1]; vSp[k] = vSp[k + 1];
            vMq[k] = vMq[k + 1]; vSq[k] = vSq[k + 1];
        }
        vMp[10] = 0.f; vSp[10] = 0.f; vMq[10] = 0.f; vSq[10] = 0.f;

        a = na; b = nb; ah = nah; bh = nbh;
    }

    return part;
}

// ---- the one kernel: 1536 L0 blocks + 516 rest blocks = 2052 ----
__global__ __launch_bounds__(256, 4) void ssim_all_kernel(
    const float* __restrict__ i1, const float* __restrict__ i2,
    double* __restrict__ acc, unsigned int* __restrict__ done,
    float* __restrict__ out, GW gw)
{
    __shared__ float2 rbs[4][80];
    const int wid = threadIdx.x >> 6;
    const int bid = blockIdx.x;

    float part;
    int lvl;
    if (bid < 1536) {
        lvl = 0;
        const int w = bid * 4 + wid;
        const int img = w >> 7;                 // 128 tiles per image
        const int tt = w & 127;
        const int tx = tt & 7, ty = tt >> 3;    // 8 cols x 16 rows
        const size_t off = (size_t)img * 512 * 512;
        part = ssim_tile_l0(i1 + off, i2 + off, tx * 64, ty * 32, gw, rbs[wid]);
    } else {
        const int w = (bid - 1536) * 4 + wid;   // 0..2063
        const int img = w / 43;
        const int r = w - img * 43;
        const size_t off = (size_t)img * 512 * 512;
        const float* P1 = i1 + off;
        const float* P2 = i2 + off;
        if (r < 32) {                            // L1: 4x8 tiles of 64x32
            lvl = 1;
            int tx = r & 3, ty = r >> 2;
            part = ssim_tile_pool<2>(P1, P2, tx * 64, ty * 32, gw, rbs[wid]);
        } else if (r < 40) {                     // L2: 2x4
            lvl = 2;
            int s_ = r - 32;
            int tx = s_ & 1, ty = s_ >> 1;
            part = ssim_tile_pool<4>(P1, P2, tx * 64, ty * 32, gw, rbs[wid]);
        } else if (r < 42) {                     // L3: 1x2
            lvl = 3;
            int ty = r - 40;
            part = ssim_tile_pool<8>(P1, P2, 0, ty * 32, gw, rbs[wid]);
        } else {                                 // L4: 1 tile
            lvl = 4;
            part = ssim_tile_pool<16>(P1, P2, 0, 0, gw, rbs[wid]);
        }
    }

#pragma unroll
    for (int o = 32; o > 0; o >>= 1) part += __shfl_down(part, o, 64);
    if ((threadIdx.x & 63) == 0) atomicAdd(acc + lvl, (double)part);

    // last block computes the loss (R12-verified pattern)
    __syncthreads();
    if (threadIdx.x == 0) {
        __threadfence();
        unsigned int prev = atomicAdd(done, 1u);
        if (prev == gridDim.x - 1) {
            __threadfence();
            double loss = 0.0;
#pragma unroll
            for (int l = 0; l < 5; ++l) {
                double cnt = 48.0 * (double)(512 >> l) * (double)(512 >> l);
                loss += 1.0 - acc[l] / cnt;
            }
            out[0] = (float)loss;
        }
    }
}

extern "C" void kernel_launch(void* const* d_in, const int* in_sizes, int n_in,
                              void* d_out, int out_size, void* d_ws, size_t ws_size,
                              hipStream_t stream)
{
    const float* img1 = (const float*)d_in[0];
    const float* img2 = (const float*)d_in[1];
    float* out = (float*)d_out;

    // 1D gaussian (sigma=1.5, k=11), matches reference construction
    GW gw;
    double gs[WIN], sum = 0.0;
    for (int i = 0; i < WIN; ++i) {
        double ax = (double)i - 5.0;
        gs[i] = exp(-(ax * ax) / 4.5);
        sum += gs[i];
    }
    for (int i = 0; i < WIN; ++i) gw.g[i] = (float)(gs[i] / sum);

    // workspace: 5 double acc @0, uint done-counter @40 (no pyramid buffers)
    double* acc = (double*)d_ws;
    unsigned int* done = (unsigned int*)((char*)d_ws + 40);

    hipMemsetAsync(d_ws, 0, 64, stream);

    hipLaunchKernelGGL(ssim_all_kernel, dim3(2052), dim3(256), 0, stream,
                       img1, img2, acc, done, out, gw);
}